// Round 7
// baseline (459.651 us; speedup 1.0000x reference)
//
#include <hip/hip_runtime.h>
#include <hip/hip_bf16.h>
#include <cstdint>
#include <cstddef>

typedef __bf16 bf16;
typedef __bf16 bf16x8 __attribute__((ext_vector_type(8)));
typedef float f32x4 __attribute__((ext_vector_type(4)));
typedef float f32x16 __attribute__((ext_vector_type(16)));

#define MFMA16(a, b, c) __builtin_amdgcn_mfma_f32_16x16x32_bf16(a, b, c, 0, 0, 0)
#define MFMA32(a, b, c) __builtin_amdgcn_mfma_f32_32x32x16_bf16(a, b, c, 0, 0, 0)

#define GLOBAL_LOAD_LDS16(gptr, lptr)                                          \
  __builtin_amdgcn_global_load_lds(                                            \
      (const __attribute__((address_space(1))) void*)(gptr),                   \
      (__attribute__((address_space(3))) void*)(lptr), 16, 0, 0)

// ---------------------------------------------------------------------------
// Merged weight transpose+convert (one launch).
// ---------------------------------------------------------------------------
__global__ void transpose_all(const float* __restrict__ w_in,
                              const float* __restrict__ w_attn,
                              const float* __restrict__ w_ff,
                              bf16* __restrict__ wt_in,
                              bf16* __restrict__ wtcat) {
  __shared__ float t[32][33];
  int id = blockIdx.x;
  const float* src; bf16* dst;
  int srcN, srccol0, LDO, mode, obase, goff, kcol0, ntn;
  if (id < 3072) {
    src = w_in; dst = wt_in; srcN = 11264; srccol0 = 0; LDO = 1024;
    mode = 0; obase = 0; goff = 0; kcol0 = 0; ntn = 96;
  } else if (id < 7168) {
    id -= 3072; src = w_in; dst = wt_in; srcN = 11264; srccol0 = 3072;
    LDO = 1024; mode = 1; obase = 3072; goff = 0; kcol0 = 0; ntn = 128;
  } else if (id < 11264) {
    id -= 7168; src = w_in; dst = wt_in; srcN = 11264; srccol0 = 7168;
    LDO = 1024; mode = 1; obase = 3072; goff = 64; kcol0 = 0; ntn = 128;
  } else if (id < 12288) {
    id -= 11264; src = w_attn; dst = wtcat; srcN = 1024; srccol0 = 0;
    LDO = 5120; mode = 0; obase = 0; goff = 0; kcol0 = 0; ntn = 32;
  } else {
    id -= 12288; src = w_ff; dst = wtcat; srcN = 1024; srccol0 = 0;
    LDO = 5120; mode = 0; obase = 0; goff = 0; kcol0 = 1024; ntn = 32;
  }
  const int n0 = (id % ntn) * 32, k0 = (id / ntn) * 32;
  const int tx = threadIdx.x, ty = threadIdx.y;
  for (int i = ty; i < 32; i += 8)
    t[i][tx] = src[(size_t)(k0 + i) * srcN + srccol0 + n0 + tx];
  __syncthreads();
  for (int i = ty; i < 32; i += 8) {
    int n = n0 + i;
    int orow = mode ? (obase + ((n >> 6) << 7) + goff + (n & 63)) : (obase + n);
    dst[(size_t)orow * LDO + kcol0 + k0 + tx] = (bf16)t[tx][i];
  }
}

// ---------------------------------------------------------------------------
// LayerNorm over D=1024, fp32 in -> bf16 out. One block (256 thr) per row.
// ---------------------------------------------------------------------------
__global__ __launch_bounds__(256) void lnorm(const float* __restrict__ x,
                                             const float* __restrict__ w,
                                             const float* __restrict__ b,
                                             bf16* __restrict__ y) {
  const int row = blockIdx.x;
  const int tid = threadIdx.x;
  const float* xr = x + (size_t)row * 1024;
  float4 v = *(const float4*)&xr[tid * 4];
  float s = v.x + v.y + v.z + v.w;
  float ss = v.x * v.x + v.y * v.y + v.z * v.z + v.w * v.w;
  __shared__ float rs[256], rss[256];
  rs[tid] = s; rss[tid] = ss;
  __syncthreads();
  for (int off = 128; off > 0; off >>= 1) {
    if (tid < off) { rs[tid] += rs[tid + off]; rss[tid] += rss[tid + off]; }
    __syncthreads();
  }
  const float mean = rs[0] * (1.f / 1024.f);
  const float var = rss[0] * (1.f / 1024.f) - mean * mean;
  const float rstd = rsqrtf(var + 1e-5f);
  const float* vp = (const float*)&v;
  for (int i = 0; i < 4; i++) {
    int c = tid * 4 + i;
    y[(size_t)row * 1024 + c] = (bf16)((vp[i] - mean) * rstd * w[c] + b[c]);
  }
}

// ---------------------------------------------------------------------------
// Flash attention v4: mfma_32x32x16, 32 q-rows/wave, 128 q/block, 128-key
// tiles. Fixed-max softmax; row-sums kept in regs (psum[16]) and reduced
// cross-lane ONCE at kernel end. XOR-swizzled LDS (bank-uniform fragment
// reads). LDP=2048 (proj holds Q|K only).
// C/D layout (m74/m101): col=lane&31, row=(reg&3)+8*(reg>>2)+4*(lane>>5).
// A: m=lane&31, k=(lane>>5)*8+j. B: n=lane&31, k=(lane>>5)*8+j.
// ---------------------------------------------------------------------------
__global__ __launch_bounds__(256) void flash_attn(const bf16* __restrict__ proj,
                                                  const bf16* __restrict__ vt,
                                                  bf16* __restrict__ hcat) {
  __shared__ __align__(16) char smem[65536];
  bf16* Ks = (bf16*)smem;            // [128][64]: (r,c)->r*64+((c>>3)^(r&7))*8+(c&7)
  bf16* Vs = (bf16*)(smem + 16384);  // [64][128]: (r,c)->r*128+((c>>3)^(r&15))*8+(c&7)
  bf16* Ps = (bf16*)(smem + 32768);  // 4 x [32][128], swizzled like Vs
  const int tid = threadIdx.x;
  const int wave = tid >> 6, lane = tid & 63;
  const int l32 = lane & 31, half = lane >> 5;
  const int q0 = blockIdx.x * 128;
  const int h = blockIdx.y, b = blockIdx.z;
  constexpr size_t LDP = 2048;
  const bf16* Qb = proj + (size_t)b * 2048 * LDP + h * 64;
  const bf16* Kb = proj + (size_t)b * 2048 * LDP + 1024 + h * 64;
  const bf16* Vt = vt + (size_t)(b * 16 + h) * 64 * 2048;

  // Q fragments (scale 1/8 folded in), 4 k-chunks of 16
  const int qrow = q0 + wave * 32 + l32;
  bf16x8 aq[4];
#pragma unroll
  for (int c = 0; c < 4; c++) {
    bf16x8 r = *(const bf16x8*)&Qb[(size_t)qrow * LDP + c * 16 + half * 8];
#pragma unroll
    for (int i = 0; i < 8; i++) aq[c][i] = (bf16)((float)r[i] * 0.125f);
  }

  f32x16 O0 = {}, O1 = {};
  float psum[16];
#pragma unroll
  for (int i = 0; i < 16; i++) psum[i] = 0.f;

  // staging maps (LDS dest = wave base + lane*16, XOR absorbed by gsrc)
  const int krow_ = wave * 8 + (lane >> 3);          // + p*32
  const int kq_ = ((lane & 7) ^ (krow_ & 7)) * 8;
  const int vrow_ = wave * 4 + (lane >> 4);          // + p*16
  const int vq_ = ((lane & 15) ^ (vrow_ & 15)) * 8;
  bf16* Pw = Ps + wave * (32 * 128);

  for (int j0 = 0; j0 < 2048; j0 += 128) {
#pragma unroll
    for (int p = 0; p < 4; p++) {
      int kr = p * 32 + krow_;
      GLOBAL_LOAD_LDS16(&Kb[(size_t)(j0 + kr) * LDP + kq_],
                        &Ks[kr * 64 + (lane & 7) * 8]);
      int vr = p * 16 + vrow_;
      GLOBAL_LOAD_LDS16(&Vt[(size_t)vr * 2048 + j0 + vq_],
                        &Vs[vr * 128 + (lane & 15) * 8]);
    }
    __syncthreads();

    // S = Q K^T : 4 key-groups of 32, K-dim 64 = 4 MFMA each
    f32x16 sacc[4];
#pragma unroll
    for (int g = 0; g < 4; g++) {
      f32x16 t = {};
      int r = g * 32 + l32;
#pragma unroll
      for (int c = 0; c < 4; c++) {
        int sl = (c * 2 + half) ^ (r & 7);
        bf16x8 bk = *(const bf16x8*)&Ks[r * 64 + sl * 8];
        t = MFMA32(aq[c], bk, t);
      }
      sacc[g] = t;
    }

    // P = exp(S) -> LDS (wave-private), psum accumulated in regs
#pragma unroll
    for (int g = 0; g < 4; g++) {
#pragma unroll
      for (int reg = 0; reg < 16; reg++) {
        float p = __expf(sacc[g][reg]);
        psum[reg] += p;
        int pr = (reg & 3) + 8 * (reg >> 2) + 4 * half;
        int pc = g * 32 + l32;
        Pw[pr * 128 + ((pc >> 3) ^ (pr & 15)) * 8 + (pc & 7)] = (bf16)p;
      }
    }

    // O += P V : 8 k-chunks of 16 keys, 2 n-groups of 32 dims
#pragma unroll
    for (int c = 0; c < 8; c++) {
      int sl = (c * 2 + half) ^ (l32 & 15);
      bf16x8 aP = *(const bf16x8*)&Pw[l32 * 128 + sl * 8];
      {
        bf16x8 bv = *(const bf16x8*)&Vs[l32 * 128 + sl * 8 + 0];  // rows 0..31
        O0 = MFMA32(aP, bv, O0);
      }
      {
        int vr = 32 + l32;
        int vsl = (c * 2 + half) ^ (vr & 15);
        bf16x8 bv = *(const bf16x8*)&Vs[vr * 128 + vsl * 8];
        O1 = MFMA32(aP, bv, O1);
      }
    }
    __syncthreads();
  }

  // final: cross-lane row-sum reduce (within 32-lane half), normalize, store
#pragma unroll
  for (int reg = 0; reg < 16; reg++) {
    float ts = psum[reg];
#pragma unroll
    for (int d = 1; d < 32; d <<= 1) ts += __shfl_xor(ts, d, 64);
    float inv = 1.f / ts;
    int qr = (reg & 3) + 8 * (reg >> 2) + 4 * half;
    size_t row = (size_t)b * 2048 + q0 + wave * 32 + qr;
    hcat[row * 5120 + h * 64 + l32] = (bf16)(O0[reg] * inv);
    hcat[row * 5120 + h * 64 + 32 + l32] = (bf16)(O1[reg] * inv);
  }
}

// ---------------------------------------------------------------------------
// proj GEMM, K=1024, swizzled LDS. Epilogue by N-tile:
//  x<16 : Q|K plain -> proj[4096][2048]
//  16<=x<24 : V transposed -> vt[b*1024 + vcol][s]
//  x>=24: ff|gate interleave -> hcat[:,1024+T*64..] = ff*gelu(gate)
// ---------------------------------------------------------------------------
__global__ __launch_bounds__(256) void gemm_proj(const bf16* __restrict__ A,
                                                 const bf16* __restrict__ Bt,
                                                 bf16* __restrict__ proj,
                                                 bf16* __restrict__ vt,
                                                 bf16* __restrict__ hcat) {
  constexpr int K = 1024, LDC = 136;
  __shared__ __align__(16) char smem[17408];
  bf16* As = (bf16*)smem;
  bf16* Bs = As + 128 * 32;
  bf16* Cs = (bf16*)smem;
  const int tid = threadIdx.x;
  const int wave = tid >> 6, lane = tid & 63;
  const int quad = lane >> 4, l16 = lane & 15;
  constexpr int NM = 4, NN = 4;
  const int wm0 = (wave >> 1) * 64, wn0 = (wave & 1) * 64;
  const size_t rowA0 = (size_t)blockIdx.y * 128;
  const size_t rowB0 = (size_t)blockIdx.x * 128;

  const int srow = wave * 16 + (lane >> 2);
  const int sq = ((lane & 3) ^ ((lane >> 3) & 3)) * 8;
  const int sslot = (lane & 3) * 8;
  const int rslot = (quad ^ ((l16 >> 1) & 3)) * 8;

  f32x4 acc[NM][NN] = {};

  for (int k0 = 0; k0 < K; k0 += 32) {
#pragma unroll
    for (int p = 0; p < 2; p++) {
      int r = p * 64 + srow;
      GLOBAL_LOAD_LDS16(&A[(rowA0 + r) * K + k0 + sq], &As[r * 32 + sslot]);
      GLOBAL_LOAD_LDS16(&Bt[(rowB0 + r) * K + k0 + sq], &Bs[r * 32 + sslot]);
    }
    __syncthreads();
    bf16x8 af[NM], bfr[NN];
#pragma unroll
    for (int i = 0; i < NM; i++)
      af[i] = *(const bf16x8*)&As[(wm0 + i * 16 + l16) * 32 + rslot];
#pragma unroll
    for (int j = 0; j < NN; j++)
      bfr[j] = *(const bf16x8*)&Bs[(wn0 + j * 16 + l16) * 32 + rslot];
#pragma unroll
    for (int i = 0; i < NM; i++)
#pragma unroll
      for (int j = 0; j < NN; j++)
        acc[i][j] = MFMA16(af[i], bfr[j], acc[i][j]);
    __syncthreads();
  }

#pragma unroll
  for (int half = 0; half < 2; half++) {
    if ((wave >> 1) == half) {
#pragma unroll
      for (int i = 0; i < NM; i++)
#pragma unroll
        for (int j = 0; j < NN; j++)
#pragma unroll
          for (int r = 0; r < 4; r++)
            Cs[(i * 16 + quad * 4 + r) * LDC + wn0 + j * 16 + l16] =
                (bf16)acc[i][j][r];
    }
    __syncthreads();
    if (blockIdx.x < 16) {
      const int c0 = (tid & 15) * 8;
#pragma unroll
      for (int it = 0; it < 4; it++) {
        int row = (tid >> 4) + it * 16;
        *(bf16x8*)&proj[(rowA0 + half * 64 + row) * 2048 + rowB0 + c0] =
            *(const bf16x8*)&Cs[row * LDC + c0];
      }
    } else if (blockIdx.x < 24) {
      // V: transpose Cs [64 s][128 vcol] -> vt[b*1024 + vcol][s]
      const int cl = tid >> 1;
      const int so = (tid & 1) * 32;
      const size_t vtrow = (rowA0 >> 11) * 1024 + rowB0 - 2048 + cl;
      const int sbase = (int)(rowA0 & 2047) + half * 64 + so;
      bf16 v[32];
#pragma unroll
      for (int i = 0; i < 32; i++) v[i] = Cs[(so + i) * LDC + cl];
      bf16* dst = vt + vtrow * 2048 + sbase;
#pragma unroll
      for (int k = 0; k < 4; k++) *(bf16x8*)&dst[k * 8] = *(bf16x8*)&v[k * 8];
    } else {
      const int T = blockIdx.x - 24;
      const int c0 = (tid & 7) * 8;
#pragma unroll
      for (int p = 0; p < 2; p++) {
        int row = (tid >> 3) + p * 32;
        bf16x8 f = *(const bf16x8*)&Cs[row * LDC + c0];
        bf16x8 g = *(const bf16x8*)&Cs[row * LDC + 64 + c0];
        bf16x8 o;
#pragma unroll
        for (int i = 0; i < 8; i++) {
          float xg = (float)g[i];
          float u = 0.7978845608f * (xg + 0.044715f * xg * xg * xg);
          float gl = xg / (1.f + __expf(-2.f * u));
          o[i] = (bf16)((float)f[i] * gl);
        }
        *(bf16x8*)&hcat[(rowA0 + half * 64 + row) * 5120 + 1024 + T * 64 + c0] = o;
      }
    }
    __syncthreads();
  }
}

// ---------------------------------------------------------------------------
// Output GEMM, split-K=4, swizzled LDS, bf16 partials, two-round epilogue.
// ---------------------------------------------------------------------------
__global__ __launch_bounds__(256) void gemm_out(const bf16* __restrict__ A,
                                                const bf16* __restrict__ Bt,
                                                bf16* __restrict__ part) {
  constexpr int LDAB = 5120, LDC = 136;
  __shared__ __align__(16) char smem[17408];
  bf16* As = (bf16*)smem;
  bf16* Bs = As + 128 * 32;
  bf16* Cs = (bf16*)smem;
  const int tid = threadIdx.x;
  const int wave = tid >> 6, lane = tid & 63;
  const int quad = lane >> 4, l16 = lane & 15;
  constexpr int NM = 4, NN = 4;
  const int wm0 = (wave >> 1) * 64, wn0 = (wave & 1) * 64;
  const size_t rowA0 = (size_t)blockIdx.y * 128;
  const size_t rowB0 = (size_t)blockIdx.x * 128;
  const int kbeg = blockIdx.z * 1280, kend = kbeg + 1280;

  const int srow = wave * 16 + (lane >> 2);
  const int sq = ((lane & 3) ^ ((lane >> 3) & 3)) * 8;
  const int sslot = (lane & 3) * 8;
  const int rslot = (quad ^ ((l16 >> 1) & 3)) * 8;

  f32x4 acc[NM][NN] = {};

  for (int k0 = kbeg; k0 < kend; k0 += 32) {
#pragma unroll
    for (int p = 0; p < 2; p++) {
      int r = p * 64 + srow;
      GLOBAL_LOAD_LDS16(&A[(rowA0 + r) * LDAB + k0 + sq], &As[r * 32 + sslot]);
      GLOBAL_LOAD_LDS16(&Bt[(rowB0 + r) * LDAB + k0 + sq], &Bs[r * 32 + sslot]);
    }
    __syncthreads();
    bf16x8 af[NM], bfr[NN];
#pragma unroll
    for (int i = 0; i < NM; i++)
      af[i] = *(const bf16x8*)&As[(wm0 + i * 16 + l16) * 32 + rslot];
#pragma unroll
    for (int j = 0; j < NN; j++)
      bfr[j] = *(const bf16x8*)&Bs[(wn0 + j * 16 + l16) * 32 + rslot];
#pragma unroll
    for (int i = 0; i < NM; i++)
#pragma unroll
      for (int j = 0; j < NN; j++)
        acc[i][j] = MFMA16(af[i], bfr[j], acc[i][j]);
    __syncthreads();
  }

  bf16* dst = part + (size_t)blockIdx.z * (4096 * 1024);
#pragma unroll
  for (int half = 0; half < 2; half++) {
    if ((wave >> 1) == half) {
#pragma unroll
      for (int i = 0; i < NM; i++)
#pragma unroll
        for (int j = 0; j < NN; j++)
#pragma unroll
          for (int r = 0; r < 4; r++)
            Cs[(i * 16 + quad * 4 + r) * LDC + wn0 + j * 16 + l16] =
                (bf16)acc[i][j][r];
    }
    __syncthreads();
    const int c0 = (tid & 15) * 8;
#pragma unroll
    for (int it = 0; it < 4; it++) {
      int row = (tid >> 4) + it * 16;
      *(bf16x8*)&dst[(rowA0 + half * 64 + row) * 1024 + rowB0 + c0] =
          *(const bf16x8*)&Cs[row * LDC + c0];
    }
    __syncthreads();
  }
}

// ---------------------------------------------------------------------------
// out = x + sum of 4 bf16 partials
// ---------------------------------------------------------------------------
__global__ __launch_bounds__(256) void reduce_out(const float* __restrict__ x,
                                                  const bf16* __restrict__ part,
                                                  float* __restrict__ out) {
  const size_t i = ((size_t)blockIdx.x * 256 + threadIdx.x) * 8;
  constexpr size_t SL = 4096 * 1024;
  float r[8];
  float4 x0 = *(const float4*)&x[i];
  float4 x1 = *(const float4*)&x[i + 4];
  r[0] = x0.x; r[1] = x0.y; r[2] = x0.z; r[3] = x0.w;
  r[4] = x1.x; r[5] = x1.y; r[6] = x1.z; r[7] = x1.w;
#pragma unroll
  for (int z = 0; z < 4; z++) {
    bf16x8 p = *(const bf16x8*)&part[z * SL + i];
#pragma unroll
    for (int k = 0; k < 8; k++) r[k] += (float)p[k];
  }
  float4 o0 = {r[0], r[1], r[2], r[3]};
  float4 o1 = {r[4], r[5], r[6], r[7]};
  *(float4*)&out[i] = o0;
  *(float4*)&out[i + 4] = o1;
}

// ---------------------------------------------------------------------------
extern "C" void kernel_launch(void* const* d_in, const int* in_sizes, int n_in,
                              void* d_out, int out_size, void* d_ws, size_t ws_size,
                              hipStream_t stream) {
  const float* x      = (const float*)d_in[0];
  const float* ln_w   = (const float*)d_in[1];
  const float* ln_b   = (const float*)d_in[2];
  const float* w_in   = (const float*)d_in[3];  // [1024,11264]
  const float* w_attn = (const float*)d_in[4];  // [1024,1024]
  const float* w_ff   = (const float*)d_in[5];  // [4096,1024]
  float* out = (float*)d_out;
  char* ws = (char*)d_ws;

  bf16* wt_in = (bf16*)(ws);                 // [11264][1024] 23068672 B
  bf16* wtcat = (bf16*)(ws + 23068672);      // [1024][5120]  10485760 B
  bf16* xn    = (bf16*)(ws + 33554432);      // [4096][1024]   8388608 B
  bf16* proj  = (bf16*)(ws + 41943040);      // [4096][2048]  16777216 B
  bf16* part  = (bf16*)(ws + 67108864);      // 4x[4096][1024] 33554432 B
  bf16* vt    = (bf16*)(ws + 100663296);     // [32][64][2048]  8388608 B
  bf16* hcat  = (bf16*)(ws + 134217728);     // [4096][5120]  41943040 B

  transpose_all<<<16384, dim3(32, 8), 0, stream>>>(w_in, w_attn, w_ff, wt_in, wtcat);
  lnorm<<<4096, 256, 0, stream>>>(x, ln_w, ln_b, xn);
  gemm_proj<<<dim3(88, 32), 256, 0, stream>>>(xn, wt_in, proj, vt, hcat);
  flash_attn<<<dim3(16, 16, 2), 256, 0, stream>>>(proj, vt, hcat);
  gemm_out<<<dim3(8, 32, 4), 256, 0, stream>>>(hcat, wtcat, part);
  reduce_out<<<2048, 256, 0, stream>>>(x, part, out);
}

// Round 8
// 426.589 us; speedup vs baseline: 1.0775x; 1.0775x over previous
//
#include <hip/hip_runtime.h>
#include <hip/hip_bf16.h>
#include <cstdint>
#include <cstddef>

typedef __bf16 bf16;
typedef __bf16 bf16x8 __attribute__((ext_vector_type(8)));
typedef float f32x4 __attribute__((ext_vector_type(4)));

#define MFMA16(a, b, c) __builtin_amdgcn_mfma_f32_16x16x32_bf16(a, b, c, 0, 0, 0)

#define GLOBAL_LOAD_LDS16(gptr, lptr)                                          \
  __builtin_amdgcn_global_load_lds(                                            \
      (const __attribute__((address_space(1))) void*)(gptr),                   \
      (__attribute__((address_space(3))) void*)(lptr), 16, 0, 0)

// ---------------------------------------------------------------------------
// Merged weight transpose+convert (one launch).
// ---------------------------------------------------------------------------
__global__ void transpose_all(const float* __restrict__ w_in,
                              const float* __restrict__ w_attn,
                              const float* __restrict__ w_ff,
                              bf16* __restrict__ wt_in,
                              bf16* __restrict__ wtcat) {
  __shared__ float t[32][33];
  int id = blockIdx.x;
  const float* src; bf16* dst;
  int srcN, srccol0, LDO, mode, obase, goff, kcol0, ntn;
  if (id < 3072) {
    src = w_in; dst = wt_in; srcN = 11264; srccol0 = 0; LDO = 1024;
    mode = 0; obase = 0; goff = 0; kcol0 = 0; ntn = 96;
  } else if (id < 7168) {
    id -= 3072; src = w_in; dst = wt_in; srcN = 11264; srccol0 = 3072;
    LDO = 1024; mode = 1; obase = 3072; goff = 0; kcol0 = 0; ntn = 128;
  } else if (id < 11264) {
    id -= 7168; src = w_in; dst = wt_in; srcN = 11264; srccol0 = 7168;
    LDO = 1024; mode = 1; obase = 3072; goff = 64; kcol0 = 0; ntn = 128;
  } else if (id < 12288) {
    id -= 11264; src = w_attn; dst = wtcat; srcN = 1024; srccol0 = 0;
    LDO = 5120; mode = 0; obase = 0; goff = 0; kcol0 = 0; ntn = 32;
  } else {
    id -= 12288; src = w_ff; dst = wtcat; srcN = 1024; srccol0 = 0;
    LDO = 5120; mode = 0; obase = 0; goff = 0; kcol0 = 1024; ntn = 32;
  }
  const int n0 = (id % ntn) * 32, k0 = (id / ntn) * 32;
  const int tx = threadIdx.x, ty = threadIdx.y;
  for (int i = ty; i < 32; i += 8)
    t[i][tx] = src[(size_t)(k0 + i) * srcN + srccol0 + n0 + tx];
  __syncthreads();
  for (int i = ty; i < 32; i += 8) {
    int n = n0 + i;
    int orow = mode ? (obase + ((n >> 6) << 7) + goff + (n & 63)) : (obase + n);
    dst[(size_t)orow * LDO + kcol0 + k0 + tx] = (bf16)t[tx][i];
  }
}

// ---------------------------------------------------------------------------
// LayerNorm over D=1024, fp32 in -> bf16 out. One block (256 thr) per row.
// ---------------------------------------------------------------------------
__global__ __launch_bounds__(256) void lnorm(const float* __restrict__ x,
                                             const float* __restrict__ w,
                                             const float* __restrict__ b,
                                             bf16* __restrict__ y) {
  const int row = blockIdx.x;
  const int tid = threadIdx.x;
  const float* xr = x + (size_t)row * 1024;
  float4 v = *(const float4*)&xr[tid * 4];
  float s = v.x + v.y + v.z + v.w;
  float ss = v.x * v.x + v.y * v.y + v.z * v.z + v.w * v.w;
  __shared__ float rs[256], rss[256];
  rs[tid] = s; rss[tid] = ss;
  __syncthreads();
  for (int off = 128; off > 0; off >>= 1) {
    if (tid < off) { rs[tid] += rs[tid + off]; rss[tid] += rss[tid + off]; }
    __syncthreads();
  }
  const float mean = rs[0] * (1.f / 1024.f);
  const float var = rss[0] * (1.f / 1024.f) - mean * mean;
  const float rstd = rsqrtf(var + 1e-5f);
  const float* vp = (const float*)&v;
  for (int i = 0; i < 4; i++) {
    int c = tid * 4 + i;
    y[(size_t)row * 1024 + c] = (bf16)((vp[i] - mean) * rstd * w[c] + b[c]);
  }
}

// ---------------------------------------------------------------------------
// V transpose: vt[b][h][d][s] = proj[b*2048+s][2048 + h*64 + d], LDP=3072
// ---------------------------------------------------------------------------
__global__ __launch_bounds__(256) void vtrans(const bf16* __restrict__ proj,
                                              bf16* __restrict__ vt) {
  __shared__ bf16 t[64][80];
  const int tid = threadIdx.x;
  const int s0 = blockIdx.x * 64;
  const int h = blockIdx.y, b = blockIdx.z;
  constexpr size_t LDP = 3072;
  const bf16* src = proj + (size_t)b * 2048 * LDP + 2048 + h * 64;
  {
    int s = tid >> 2, d0 = (tid & 3) * 16;
    *(bf16x8*)&t[s][d0]     = *(const bf16x8*)&src[(size_t)(s0 + s) * LDP + d0];
    *(bf16x8*)&t[s][d0 + 8] = *(const bf16x8*)&src[(size_t)(s0 + s) * LDP + d0 + 8];
  }
  __syncthreads();
  {
    int d = tid >> 2, sb = (tid & 3) * 16;
    bf16* dst = vt + ((size_t)(b * 16 + h) * 64 + d) * 2048 + s0 + sb;
    bf16x8 o0, o1;
    for (int i = 0; i < 8; i++) { o0[i] = t[sb + i][d]; o1[i] = t[sb + 8 + i][d]; }
    *(bf16x8*)&dst[0] = o0;
    *(bf16x8*)&dst[8] = o1;
  }
}

// ---------------------------------------------------------------------------
// Flash attention (fixed-max softmax), 128-key tiles, global_load_lds staging
// with XOR-swizzled conflict-free LDS. 256 thr, 64 q-rows/block. LDP=3072.
// (R6-proven version.)
// ---------------------------------------------------------------------------
__global__ __launch_bounds__(256) void flash_attn(const bf16* __restrict__ proj,
                                                  const bf16* __restrict__ vt,
                                                  bf16* __restrict__ hcat) {
  __shared__ __align__(16) char smem[50176];
  bf16* Ks = (bf16*)smem;                  // [128][64] swizzled
  bf16* Vs = (bf16*)(smem + 16384);        // [64][128] swizzled
  bf16* Ps = (bf16*)(smem + 32768);        // [4][16][136]
  const int tid = threadIdx.x;
  const int wave = tid >> 6, lane = tid & 63;
  const int quad = lane >> 4, l16 = lane & 15;
  const int q0 = blockIdx.x * 64;
  const int h = blockIdx.y, b = blockIdx.z;
  constexpr size_t LDP = 3072;
  const bf16* Qb = proj + (size_t)b * 2048 * LDP + h * 64;
  const bf16* Kb = proj + (size_t)b * 2048 * LDP + 1024 + h * 64;
  const bf16* Vt = vt + (size_t)(b * 16 + h) * 64 * 2048;

  const int qrow = q0 + wave * 16 + l16;
  bf16x8 aq0r = *(const bf16x8*)&Qb[(size_t)qrow * LDP + quad * 8];
  bf16x8 aq1r = *(const bf16x8*)&Qb[(size_t)qrow * LDP + 32 + quad * 8];
  bf16x8 aq0, aq1;
#pragma unroll
  for (int i = 0; i < 8; i++) {
    aq0[i] = (bf16)((float)aq0r[i] * 0.125f);
    aq1[i] = (bf16)((float)aq1r[i] * 0.125f);
  }

  f32x4 O[4] = {};
  float lrow[4] = {0.f, 0.f, 0.f, 0.f};

  const int krow_ = wave * 8 + (lane >> 3);
  const int kq_ = ((lane & 7) ^ (krow_ & 7)) * 8;
  const int vrow_ = wave * 4 + (lane >> 4);
  const int vq_ = ((lane & 15) ^ (vrow_ & 15)) * 8;
  const int ks0 = (quad ^ (l16 & 7)) * 8;
  const int ks1 = ((quad + 4) ^ (l16 & 7)) * 8;

  for (int j0 = 0; j0 < 2048; j0 += 128) {
#pragma unroll
    for (int p = 0; p < 4; p++) {
      int kr = p * 32 + krow_;
      GLOBAL_LOAD_LDS16(&Kb[(size_t)(j0 + kr) * LDP + kq_],
                        &Ks[kr * 64 + (lane & 7) * 8]);
      int vr = p * 16 + vrow_;
      GLOBAL_LOAD_LDS16(&Vt[(size_t)vr * 2048 + j0 + vq_],
                        &Vs[vr * 128 + (lane & 15) * 8]);
    }
    __syncthreads();

    f32x4 sa[8];
#pragma unroll
    for (int nt = 0; nt < 8; nt++) {
      int r = nt * 16 + l16;
      bf16x8 bk0 = *(const bf16x8*)&Ks[r * 64 + (quad ^ (r & 7)) * 8];
      bf16x8 bk1 = *(const bf16x8*)&Ks[r * 64 + ((quad + 4) ^ (r & 7)) * 8];
      f32x4 t = {};
      t = MFMA16(aq0, bk0, t);
      sa[nt] = MFMA16(aq1, bk1, t);
    }

    bf16* Pw = Ps + wave * (16 * 136);
#pragma unroll
    for (int r = 0; r < 4; r++) {
      bf16* pr = &Pw[(quad * 4 + r) * 136];
      float ts = 0.f;
#pragma unroll
      for (int nt = 0; nt < 8; nt++) {
        float p = __expf(sa[nt][r]);
        pr[nt * 16 + l16] = (bf16)p;
        ts += p;
      }
#pragma unroll
      for (int d = 1; d < 16; d <<= 1) ts += __shfl_xor(ts, d, 64);
      lrow[r] += ts;
    }

#pragma unroll
    for (int kg = 0; kg < 4; kg++) {
      bf16x8 aP = *(const bf16x8*)&Pw[l16 * 136 + kg * 32 + quad * 8];
#pragma unroll
      for (int nb = 0; nb < 4; nb++) {
        int vrr = nb * 16 + l16;
        int vsl = ((kg * 4 + quad) ^ (vrr & 15)) * 8;
        bf16x8 bv = *(const bf16x8*)&Vs[vrr * 128 + vsl];
        O[nb] = MFMA16(aP, bv, O[nb]);
      }
    }
    __syncthreads();
  }

#pragma unroll
  for (int r = 0; r < 4; r++) {
    float inv = 1.f / lrow[r];
    size_t row = (size_t)b * 2048 + q0 + wave * 16 + quad * 4 + r;
#pragma unroll
    for (int nb = 0; nb < 4; nb++)
      hcat[row * 5120 + h * 64 + nb * 16 + l16] = (bf16)(O[nb][r] * inv);
  }
}

// ---------------------------------------------------------------------------
// proj GEMM, K=1024, BK=64 (16 iters — halves barrier-drain count vs BK=32),
// XOR-swizzled LDS [128][64] (slice s of row r at slot s^(r&7); all fragment
// reads 2-way max = free). Epilogue: x<24 plain -> proj; x>=24 ff|gate gelu.
// ---------------------------------------------------------------------------
__global__ __launch_bounds__(256) void gemm_proj(const bf16* __restrict__ A,
                                                 const bf16* __restrict__ Bt,
                                                 bf16* __restrict__ proj,
                                                 bf16* __restrict__ hcat) {
  constexpr int K = 1024, LDC = 136;
  __shared__ __align__(16) char smem[32768];
  bf16* As = (bf16*)smem;            // [128][64] swizzled, 16384 B
  bf16* Bs = As + 128 * 64;          // [128][64] swizzled, 16384 B
  bf16* Cs = (bf16*)smem;            // [64][136] epilogue reuse
  const int tid = threadIdx.x;
  const int wave = tid >> 6, lane = tid & 63;
  const int quad = lane >> 4, l16 = lane & 15;
  constexpr int NM = 4, NN = 4;
  const int wm0 = (wave >> 1) * 64, wn0 = (wave & 1) * 64;
  const size_t rowA0 = (size_t)blockIdx.y * 128;
  const size_t rowB0 = (size_t)blockIdx.x * 128;

  // staging: thread stages 16B chunk; row = p*32 + tid>>3, slot = tid&7.
  // LDS byte = p*4096 + wave*1024 + lane*16 (wave-uniform base + lane*16).
  const int srow = tid >> 3;
  const int sq = ((tid & 7) ^ (srow & 7)) * 8;   // global col chunk (XOR-absorbed)
  const int sslot = (tid & 7) * 8;

  f32x4 acc[NM][NN] = {};

  for (int k0 = 0; k0 < K; k0 += 64) {
#pragma unroll
    for (int p = 0; p < 4; p++) {
      int r = p * 32 + srow;
      GLOBAL_LOAD_LDS16(&A[(rowA0 + r) * K + k0 + sq], &As[r * 64 + sslot]);
      GLOBAL_LOAD_LDS16(&Bt[(rowB0 + r) * K + k0 + sq], &Bs[r * 64 + sslot]);
    }
    __syncthreads();
#pragma unroll
    for (int c = 0; c < 2; c++) {
      bf16x8 af[NM], bfr[NN];
#pragma unroll
      for (int i = 0; i < NM; i++) {
        int r = wm0 + i * 16 + l16;
        af[i] = *(const bf16x8*)&As[r * 64 + ((c * 4 + quad) ^ (r & 7)) * 8];
      }
#pragma unroll
      for (int j = 0; j < NN; j++) {
        int r = wn0 + j * 16 + l16;
        bfr[j] = *(const bf16x8*)&Bs[r * 64 + ((c * 4 + quad) ^ (r & 7)) * 8];
      }
#pragma unroll
      for (int i = 0; i < NM; i++)
#pragma unroll
        for (int j = 0; j < NN; j++)
          acc[i][j] = MFMA16(af[i], bfr[j], acc[i][j]);
    }
    __syncthreads();
  }

#pragma unroll
  for (int half = 0; half < 2; half++) {
    if ((wave >> 1) == half) {
#pragma unroll
      for (int i = 0; i < NM; i++)
#pragma unroll
        for (int j = 0; j < NN; j++)
#pragma unroll
          for (int r = 0; r < 4; r++)
            Cs[(i * 16 + quad * 4 + r) * LDC + wn0 + j * 16 + l16] =
                (bf16)acc[i][j][r];
    }
    __syncthreads();
    if (blockIdx.x < 24) {
      const int c0 = (tid & 15) * 8;
#pragma unroll
      for (int it = 0; it < 4; it++) {
        int row = (tid >> 4) + it * 16;
        *(bf16x8*)&proj[(rowA0 + half * 64 + row) * 3072 + rowB0 + c0] =
            *(const bf16x8*)&Cs[row * LDC + c0];
      }
    } else {
      const int T = blockIdx.x - 24;
      const int c0 = (tid & 7) * 8;
#pragma unroll
      for (int p = 0; p < 2; p++) {
        int row = (tid >> 3) + p * 32;
        bf16x8 f = *(const bf16x8*)&Cs[row * LDC + c0];
        bf16x8 g = *(const bf16x8*)&Cs[row * LDC + 64 + c0];
        bf16x8 o;
#pragma unroll
        for (int i = 0; i < 8; i++) {
          float xg = (float)g[i];
          float u = 0.7978845608f * (xg + 0.044715f * xg * xg * xg);
          float gl = xg / (1.f + __expf(-2.f * u));
          o[i] = (bf16)((float)f[i] * gl);
        }
        *(bf16x8*)&hcat[(rowA0 + half * 64 + row) * 5120 + 1024 + T * 64 + c0] = o;
      }
    }
    __syncthreads();
  }
}

// ---------------------------------------------------------------------------
// Output GEMM, split-K=4, BK=64 (20 iters), swizzled LDS, bf16 partials.
// part[z][M][1024] = A[M,5120] @ Bt[1024,5120]^T over K-slice z.
// ---------------------------------------------------------------------------
__global__ __launch_bounds__(256) void gemm_out(const bf16* __restrict__ A,
                                                const bf16* __restrict__ Bt,
                                                bf16* __restrict__ part) {
  constexpr int LDAB = 5120, LDC = 136;
  __shared__ __align__(16) char smem[32768];
  bf16* As = (bf16*)smem;
  bf16* Bs = As + 128 * 64;
  bf16* Cs = (bf16*)smem;
  const int tid = threadIdx.x;
  const int wave = tid >> 6, lane = tid & 63;
  const int quad = lane >> 4, l16 = lane & 15;
  constexpr int NM = 4, NN = 4;
  const int wm0 = (wave >> 1) * 64, wn0 = (wave & 1) * 64;
  const size_t rowA0 = (size_t)blockIdx.y * 128;
  const size_t rowB0 = (size_t)blockIdx.x * 128;
  const int kbeg = blockIdx.z * 1280, kend = kbeg + 1280;

  const int srow = tid >> 3;
  const int sq = ((tid & 7) ^ (srow & 7)) * 8;
  const int sslot = (tid & 7) * 8;

  f32x4 acc[NM][NN] = {};

  for (int k0 = kbeg; k0 < kend; k0 += 64) {
#pragma unroll
    for (int p = 0; p < 4; p++) {
      int r = p * 32 + srow;
      GLOBAL_LOAD_LDS16(&A[(rowA0 + r) * LDAB + k0 + sq], &As[r * 64 + sslot]);
      GLOBAL_LOAD_LDS16(&Bt[(rowB0 + r) * LDAB + k0 + sq], &Bs[r * 64 + sslot]);
    }
    __syncthreads();
#pragma unroll
    for (int c = 0; c < 2; c++) {
      bf16x8 af[NM], bfr[NN];
#pragma unroll
      for (int i = 0; i < NM; i++) {
        int r = wm0 + i * 16 + l16;
        af[i] = *(const bf16x8*)&As[r * 64 + ((c * 4 + quad) ^ (r & 7)) * 8];
      }
#pragma unroll
      for (int j = 0; j < NN; j++) {
        int r = wn0 + j * 16 + l16;
        bfr[j] = *(const bf16x8*)&Bs[r * 64 + ((c * 4 + quad) ^ (r & 7)) * 8];
      }
#pragma unroll
      for (int i = 0; i < NM; i++)
#pragma unroll
        for (int j = 0; j < NN; j++)
          acc[i][j] = MFMA16(af[i], bfr[j], acc[i][j]);
    }
    __syncthreads();
  }

  bf16* dst = part + (size_t)blockIdx.z * (4096 * 1024);
#pragma unroll
  for (int half = 0; half < 2; half++) {
    if ((wave >> 1) == half) {
#pragma unroll
      for (int i = 0; i < NM; i++)
#pragma unroll
        for (int j = 0; j < NN; j++)
#pragma unroll
          for (int r = 0; r < 4; r++)
            Cs[(i * 16 + quad * 4 + r) * LDC + wn0 + j * 16 + l16] =
                (bf16)acc[i][j][r];
    }
    __syncthreads();
    const int c0 = (tid & 15) * 8;
#pragma unroll
    for (int it = 0; it < 4; it++) {
      int row = (tid >> 4) + it * 16;
      *(bf16x8*)&dst[(rowA0 + half * 64 + row) * 1024 + rowB0 + c0] =
          *(const bf16x8*)&Cs[row * LDC + c0];
    }
    __syncthreads();
  }
}

// ---------------------------------------------------------------------------
// out = x + sum of 4 bf16 partials
// ---------------------------------------------------------------------------
__global__ __launch_bounds__(256) void reduce_out(const float* __restrict__ x,
                                                  const bf16* __restrict__ part,
                                                  float* __restrict__ out) {
  const size_t i = ((size_t)blockIdx.x * 256 + threadIdx.x) * 8;
  constexpr size_t SL = 4096 * 1024;
  float r[8];
  float4 x0 = *(const float4*)&x[i];
  float4 x1 = *(const float4*)&x[i + 4];
  r[0] = x0.x; r[1] = x0.y; r[2] = x0.z; r[3] = x0.w;
  r[4] = x1.x; r[5] = x1.y; r[6] = x1.z; r[7] = x1.w;
#pragma unroll
  for (int z = 0; z < 4; z++) {
    bf16x8 p = *(const bf16x8*)&part[z * SL + i];
#pragma unroll
    for (int k = 0; k < 8; k++) r[k] += (float)p[k];
  }
  float4 o0 = {r[0], r[1], r[2], r[3]};
  float4 o1 = {r[4], r[5], r[6], r[7]};
  *(float4*)&out[i] = o0;
  *(float4*)&out[i + 4] = o1;
}

// ---------------------------------------------------------------------------
extern "C" void kernel_launch(void* const* d_in, const int* in_sizes, int n_in,
                              void* d_out, int out_size, void* d_ws, size_t ws_size,
                              hipStream_t stream) {
  const float* x      = (const float*)d_in[0];
  const float* ln_w   = (const float*)d_in[1];
  const float* ln_b   = (const float*)d_in[2];
  const float* w_in   = (const float*)d_in[3];  // [1024,11264]
  const float* w_attn = (const float*)d_in[4];  // [1024,1024]
  const float* w_ff   = (const float*)d_in[5];  // [4096,1024]
  float* out = (float*)d_out;
  char* ws = (char*)d_ws;

  bf16* wt_in = (bf16*)(ws);                 // [11264][1024] 23068672 B
  bf16* wtcat = (bf16*)(ws + 23068672);      // [1024][5120]  10485760 B
  bf16* xn    = (bf16*)(ws + 33554432);      // [4096][1024]   8388608 B
  bf16* proj  = (bf16*)(ws + 41943040);      // [4096][3072]  25165824 B
  bf16* part  = (bf16*)(ws + 67108864);      // 4x[4096][1024] 33554432 B
  bf16* vt    = (bf16*)(ws + 100663296);     // [32][64][2048]  8388608 B
  bf16* hcat  = (bf16*)(ws + 134217728);     // [4096][5120]  41943040 B

  transpose_all<<<16384, dim3(32, 8), 0, stream>>>(w_in, w_attn, w_ff, wt_in, wtcat);
  lnorm<<<4096, 256, 0, stream>>>(x, ln_w, ln_b, xn);
  gemm_proj<<<dim3(88, 32), 256, 0, stream>>>(xn, wt_in, proj, hcat);
  vtrans<<<dim3(32, 16, 2), 256, 0, stream>>>(proj, vt);
  flash_attn<<<dim3(32, 16, 2), 256, 0, stream>>>(proj, vt, hcat);
  gemm_out<<<dim3(8, 32, 4), 256, 0, stream>>>(hcat, wtcat, part);
  reduce_out<<<2048, 256, 0, stream>>>(x, part, out);
}

// Round 9
// 399.351 us; speedup vs baseline: 1.1510x; 1.0682x over previous
//
#include <hip/hip_runtime.h>
#include <hip/hip_bf16.h>
#include <cstdint>
#include <cstddef>

typedef __bf16 bf16;
typedef __bf16 bf16x8 __attribute__((ext_vector_type(8)));
typedef float f32x4 __attribute__((ext_vector_type(4)));

#define MFMA16(a, b, c) __builtin_amdgcn_mfma_f32_16x16x32_bf16(a, b, c, 0, 0, 0)

#define GLOBAL_LOAD_LDS16(gptr, lptr)                                          \
  __builtin_amdgcn_global_load_lds(                                            \
      (const __attribute__((address_space(1))) void*)(gptr),                   \
      (__attribute__((address_space(3))) void*)(lptr), 16, 0, 0)

// ---------------------------------------------------------------------------
// prep: blocks 0..16383 = weight transpose+convert; 16384..20479 = LayerNorm.
// ---------------------------------------------------------------------------
__global__ __launch_bounds__(256) void prep(const float* __restrict__ w_in,
                                            const float* __restrict__ w_attn,
                                            const float* __restrict__ w_ff,
                                            bf16* __restrict__ wt_in,
                                            bf16* __restrict__ wtcat,
                                            const float* __restrict__ x,
                                            const float* __restrict__ ln_w,
                                            const float* __restrict__ ln_b,
                                            bf16* __restrict__ xn) {
  __shared__ __align__(16) char sm[4352];
  if (blockIdx.x < 16384) {
    float(*t)[33] = (float(*)[33])sm;
    int id = blockIdx.x;
    const float* src; bf16* dst;
    int srcN, srccol0, LDO, mode, obase, goff, kcol0, ntn;
    if (id < 3072) {
      src = w_in; dst = wt_in; srcN = 11264; srccol0 = 0; LDO = 1024;
      mode = 0; obase = 0; goff = 0; kcol0 = 0; ntn = 96;
    } else if (id < 7168) {
      id -= 3072; src = w_in; dst = wt_in; srcN = 11264; srccol0 = 3072;
      LDO = 1024; mode = 1; obase = 3072; goff = 0; kcol0 = 0; ntn = 128;
    } else if (id < 11264) {
      id -= 7168; src = w_in; dst = wt_in; srcN = 11264; srccol0 = 7168;
      LDO = 1024; mode = 1; obase = 3072; goff = 64; kcol0 = 0; ntn = 128;
    } else if (id < 12288) {
      id -= 11264; src = w_attn; dst = wtcat; srcN = 1024; srccol0 = 0;
      LDO = 5120; mode = 0; obase = 0; goff = 0; kcol0 = 0; ntn = 32;
    } else {
      id -= 12288; src = w_ff; dst = wtcat; srcN = 1024; srccol0 = 0;
      LDO = 5120; mode = 0; obase = 0; goff = 0; kcol0 = 1024; ntn = 32;
    }
    const int n0 = (id % ntn) * 32, k0 = (id / ntn) * 32;
    const int tx = threadIdx.x & 31, ty = threadIdx.x >> 5;
    for (int i = ty; i < 32; i += 8)
      t[i][tx] = src[(size_t)(k0 + i) * srcN + srccol0 + n0 + tx];
    __syncthreads();
    for (int i = ty; i < 32; i += 8) {
      int n = n0 + i;
      int orow = mode ? (obase + ((n >> 6) << 7) + goff + (n & 63)) : (obase + n);
      dst[(size_t)orow * LDO + kcol0 + k0 + tx] = (bf16)t[tx][i];
    }
  } else {
    float* rs = (float*)sm;          // [256]
    float* rss = rs + 256;           // [256]
    const int row = blockIdx.x - 16384;
    const int tid = threadIdx.x;
    const float* xr = x + (size_t)row * 1024;
    float4 v = *(const float4*)&xr[tid * 4];
    float s = v.x + v.y + v.z + v.w;
    float ss = v.x * v.x + v.y * v.y + v.z * v.z + v.w * v.w;
    rs[tid] = s; rss[tid] = ss;
    __syncthreads();
    for (int off = 128; off > 0; off >>= 1) {
      if (tid < off) { rs[tid] += rs[tid + off]; rss[tid] += rss[tid + off]; }
      __syncthreads();
    }
    const float mean = rs[0] * (1.f / 1024.f);
    const float var = rss[0] * (1.f / 1024.f) - mean * mean;
    const float rstd = rsqrtf(var + 1e-5f);
    const float* vp = (const float*)&v;
    for (int i = 0; i < 4; i++) {
      int c = tid * 4 + i;
      xn[(size_t)row * 1024 + c] = (bf16)((vp[i] - mean) * rstd * ln_w[c] + ln_b[c]);
    }
  }
}

// ---------------------------------------------------------------------------
// V transpose: vt[b][h][d][s] = proj[b*2048+s][2048 + h*64 + d], LDP=3072
// ---------------------------------------------------------------------------
__global__ __launch_bounds__(256) void vtrans(const bf16* __restrict__ proj,
                                              bf16* __restrict__ vt) {
  __shared__ bf16 t[64][80];
  const int tid = threadIdx.x;
  const int s0 = blockIdx.x * 64;
  const int h = blockIdx.y, b = blockIdx.z;
  constexpr size_t LDP = 3072;
  const bf16* src = proj + (size_t)b * 2048 * LDP + 2048 + h * 64;
  {
    int s = tid >> 2, d0 = (tid & 3) * 16;
    *(bf16x8*)&t[s][d0]     = *(const bf16x8*)&src[(size_t)(s0 + s) * LDP + d0];
    *(bf16x8*)&t[s][d0 + 8] = *(const bf16x8*)&src[(size_t)(s0 + s) * LDP + d0 + 8];
  }
  __syncthreads();
  {
    int d = tid >> 2, sb = (tid & 3) * 16;
    bf16* dst = vt + ((size_t)(b * 16 + h) * 64 + d) * 2048 + s0 + sb;
    bf16x8 o0, o1;
    for (int i = 0; i < 8; i++) { o0[i] = t[sb + i][d]; o1[i] = t[sb + 8 + i][d]; }
    *(bf16x8*)&dst[0] = o0;
    *(bf16x8*)&dst[8] = o1;
  }
}

// ---------------------------------------------------------------------------
// Flash attention (fixed-max softmax), 128-key tiles, global_load_lds +
// XOR-swizzled LDS. Row-sum kept as per-lane partials; ONE cross-lane
// reduce at kernel end (softmax l is linear under fixed max).
// ---------------------------------------------------------------------------
__global__ __launch_bounds__(256) void flash_attn(const bf16* __restrict__ proj,
                                                  const bf16* __restrict__ vt,
                                                  bf16* __restrict__ hcat) {
  __shared__ __align__(16) char smem[50176];
  bf16* Ks = (bf16*)smem;                  // [128][64] swizzled
  bf16* Vs = (bf16*)(smem + 16384);        // [64][128] swizzled
  bf16* Ps = (bf16*)(smem + 32768);        // [4][16][136]
  const int tid = threadIdx.x;
  const int wave = tid >> 6, lane = tid & 63;
  const int quad = lane >> 4, l16 = lane & 15;
  const int q0 = blockIdx.x * 64;
  const int h = blockIdx.y, b = blockIdx.z;
  constexpr size_t LDP = 3072;
  const bf16* Qb = proj + (size_t)b * 2048 * LDP + h * 64;
  const bf16* Kb = proj + (size_t)b * 2048 * LDP + 1024 + h * 64;
  const bf16* Vt = vt + (size_t)(b * 16 + h) * 64 * 2048;

  const int qrow = q0 + wave * 16 + l16;
  bf16x8 aq0r = *(const bf16x8*)&Qb[(size_t)qrow * LDP + quad * 8];
  bf16x8 aq1r = *(const bf16x8*)&Qb[(size_t)qrow * LDP + 32 + quad * 8];
  bf16x8 aq0, aq1;
#pragma unroll
  for (int i = 0; i < 8; i++) {
    aq0[i] = (bf16)((float)aq0r[i] * 0.125f);
    aq1[i] = (bf16)((float)aq1r[i] * 0.125f);
  }

  f32x4 O[4] = {};
  float plrow[4] = {0.f, 0.f, 0.f, 0.f};  // per-lane partial row-sums

  const int krow_ = wave * 8 + (lane >> 3);
  const int kq_ = ((lane & 7) ^ (krow_ & 7)) * 8;
  const int vrow_ = wave * 4 + (lane >> 4);
  const int vq_ = ((lane & 15) ^ (vrow_ & 15)) * 8;

  for (int j0 = 0; j0 < 2048; j0 += 128) {
#pragma unroll
    for (int p = 0; p < 4; p++) {
      int kr = p * 32 + krow_;
      GLOBAL_LOAD_LDS16(&Kb[(size_t)(j0 + kr) * LDP + kq_],
                        &Ks[kr * 64 + (lane & 7) * 8]);
      int vr = p * 16 + vrow_;
      GLOBAL_LOAD_LDS16(&Vt[(size_t)vr * 2048 + j0 + vq_],
                        &Vs[vr * 128 + (lane & 15) * 8]);
    }
    __syncthreads();

    f32x4 sa[8];
#pragma unroll
    for (int nt = 0; nt < 8; nt++) {
      int r = nt * 16 + l16;
      bf16x8 bk0 = *(const bf16x8*)&Ks[r * 64 + (quad ^ (r & 7)) * 8];
      bf16x8 bk1 = *(const bf16x8*)&Ks[r * 64 + ((quad + 4) ^ (r & 7)) * 8];
      f32x4 t = {};
      t = MFMA16(aq0, bk0, t);
      sa[nt] = MFMA16(aq1, bk1, t);
    }

    bf16* Pw = Ps + wave * (16 * 136);
#pragma unroll
    for (int r = 0; r < 4; r++) {
      bf16* pr = &Pw[(quad * 4 + r) * 136];
      float ts = 0.f;
#pragma unroll
      for (int nt = 0; nt < 8; nt++) {
        float p = __expf(sa[nt][r]);
        pr[nt * 16 + l16] = (bf16)p;
        ts += p;
      }
      plrow[r] += ts;  // defer cross-lane reduce to epilogue
    }

#pragma unroll
    for (int kg = 0; kg < 4; kg++) {
      bf16x8 aP = *(const bf16x8*)&Pw[l16 * 136 + kg * 32 + quad * 8];
#pragma unroll
      for (int nb = 0; nb < 4; nb++) {
        int vrr = nb * 16 + l16;
        int vsl = ((kg * 4 + quad) ^ (vrr & 15)) * 8;
        bf16x8 bv = *(const bf16x8*)&Vs[vrr * 128 + vsl];
        O[nb] = MFMA16(aP, bv, O[nb]);
      }
    }
    __syncthreads();
  }

#pragma unroll
  for (int r = 0; r < 4; r++) {
    float ts = plrow[r];
#pragma unroll
    for (int d = 1; d < 16; d <<= 1) ts += __shfl_xor(ts, d, 64);
    float inv = 1.f / ts;
    size_t row = (size_t)b * 2048 + q0 + wave * 16 + quad * 4 + r;
#pragma unroll
    for (int nb = 0; nb < 4; nb++)
      hcat[row * 5120 + h * 64 + nb * 16 + l16] = (bf16)(O[nb][r] * inv);
  }
}

// ---------------------------------------------------------------------------
// proj GEMM (R6-proven): K=1024, BK=32, swizzled LDS, 64x136 Cs two-round
// epilogue. tiles x<24: plain -> proj[4096][3072]; x>=24: ff|gate gelu.
// ---------------------------------------------------------------------------
__global__ __launch_bounds__(256) void gemm_proj(const bf16* __restrict__ A,
                                                 const bf16* __restrict__ Bt,
                                                 bf16* __restrict__ proj,
                                                 bf16* __restrict__ hcat) {
  constexpr int K = 1024, LDC = 136;
  __shared__ __align__(16) char smem[17408];
  bf16* As = (bf16*)smem;            // [128][32] swizzled
  bf16* Bs = As + 128 * 32;          // [128][32] swizzled
  bf16* Cs = (bf16*)smem;            // [64][136] epilogue reuse
  const int tid = threadIdx.x;
  const int wave = tid >> 6, lane = tid & 63;
  const int quad = lane >> 4, l16 = lane & 15;
  constexpr int NM = 4, NN = 4;
  const int wm0 = (wave >> 1) * 64, wn0 = (wave & 1) * 64;
  const size_t rowA0 = (size_t)blockIdx.y * 128;
  const size_t rowB0 = (size_t)blockIdx.x * 128;

  const int srow = wave * 16 + (lane >> 2);
  const int sq = ((lane & 3) ^ ((lane >> 3) & 3)) * 8;
  const int sslot = (lane & 3) * 8;
  const int rslot = (quad ^ ((l16 >> 1) & 3)) * 8;

  f32x4 acc[NM][NN] = {};

  for (int k0 = 0; k0 < K; k0 += 32) {
#pragma unroll
    for (int p = 0; p < 2; p++) {
      int r = p * 64 + srow;
      GLOBAL_LOAD_LDS16(&A[(rowA0 + r) * K + k0 + sq], &As[r * 32 + sslot]);
      GLOBAL_LOAD_LDS16(&Bt[(rowB0 + r) * K + k0 + sq], &Bs[r * 32 + sslot]);
    }
    __syncthreads();
    bf16x8 af[NM], bfr[NN];
#pragma unroll
    for (int i = 0; i < NM; i++)
      af[i] = *(const bf16x8*)&As[(wm0 + i * 16 + l16) * 32 + rslot];
#pragma unroll
    for (int j = 0; j < NN; j++)
      bfr[j] = *(const bf16x8*)&Bs[(wn0 + j * 16 + l16) * 32 + rslot];
#pragma unroll
    for (int i = 0; i < NM; i++)
#pragma unroll
      for (int j = 0; j < NN; j++)
        acc[i][j] = MFMA16(af[i], bfr[j], acc[i][j]);
    __syncthreads();
  }

#pragma unroll
  for (int half = 0; half < 2; half++) {
    if ((wave >> 1) == half) {
#pragma unroll
      for (int i = 0; i < NM; i++)
#pragma unroll
        for (int j = 0; j < NN; j++)
#pragma unroll
          for (int r = 0; r < 4; r++)
            Cs[(i * 16 + quad * 4 + r) * LDC + wn0 + j * 16 + l16] =
                (bf16)acc[i][j][r];
    }
    __syncthreads();
    if (blockIdx.x < 24) {
      const int c0 = (tid & 15) * 8;
#pragma unroll
      for (int it = 0; it < 4; it++) {
        int row = (tid >> 4) + it * 16;
        *(bf16x8*)&proj[(rowA0 + half * 64 + row) * 3072 + rowB0 + c0] =
            *(const bf16x8*)&Cs[row * LDC + c0];
      }
    } else {
      const int T = blockIdx.x - 24;
      const int c0 = (tid & 7) * 8;
#pragma unroll
      for (int p = 0; p < 2; p++) {
        int row = (tid >> 3) + p * 32;
        bf16x8 f = *(const bf16x8*)&Cs[row * LDC + c0];
        bf16x8 g = *(const bf16x8*)&Cs[row * LDC + 64 + c0];
        bf16x8 o;
#pragma unroll
        for (int i = 0; i < 8; i++) {
          float xg = (float)g[i];
          float u = 0.7978845608f * (xg + 0.044715f * xg * xg * xg);
          float gl = xg / (1.f + __expf(-2.f * u));
          o[i] = (bf16)((float)f[i] * gl);
        }
        *(bf16x8*)&hcat[(rowA0 + half * 64 + row) * 5120 + 1024 + T * 64 + c0] = o;
      }
    }
    __syncthreads();
  }
}

// ---------------------------------------------------------------------------
// Output GEMM (R8-proven): split-K=4, BK=64, swizzled LDS, bf16 partials.
// ---------------------------------------------------------------------------
__global__ __launch_bounds__(256) void gemm_out(const bf16* __restrict__ A,
                                                const bf16* __restrict__ Bt,
                                                bf16* __restrict__ part) {
  constexpr int LDAB = 5120, LDC = 136;
  __shared__ __align__(16) char smem[32768];
  bf16* As = (bf16*)smem;
  bf16* Bs = As + 128 * 64;
  bf16* Cs = (bf16*)smem;
  const int tid = threadIdx.x;
  const int wave = tid >> 6, lane = tid & 63;
  const int quad = lane >> 4, l16 = lane & 15;
  constexpr int NM = 4, NN = 4;
  const int wm0 = (wave >> 1) * 64, wn0 = (wave & 1) * 64;
  const size_t rowA0 = (size_t)blockIdx.y * 128;
  const size_t rowB0 = (size_t)blockIdx.x * 128;
  const int kbeg = blockIdx.z * 1280, kend = kbeg + 1280;

  const int srow = tid >> 3;
  const int sq = ((tid & 7) ^ (srow & 7)) * 8;
  const int sslot = (tid & 7) * 8;

  f32x4 acc[NM][NN] = {};

  for (int k0 = kbeg; k0 < kend; k0 += 64) {
#pragma unroll
    for (int p = 0; p < 4; p++) {
      int r = p * 32 + srow;
      GLOBAL_LOAD_LDS16(&A[(rowA0 + r) * LDAB + k0 + sq], &As[r * 64 + sslot]);
      GLOBAL_LOAD_LDS16(&Bt[(rowB0 + r) * LDAB + k0 + sq], &Bs[r * 64 + sslot]);
    }
    __syncthreads();
#pragma unroll
    for (int c = 0; c < 2; c++) {
      bf16x8 af[NM], bfr[NN];
#pragma unroll
      for (int i = 0; i < NM; i++) {
        int r = wm0 + i * 16 + l16;
        af[i] = *(const bf16x8*)&As[r * 64 + ((c * 4 + quad) ^ (r & 7)) * 8];
      }
#pragma unroll
      for (int j = 0; j < NN; j++) {
        int r = wn0 + j * 16 + l16;
        bfr[j] = *(const bf16x8*)&Bs[r * 64 + ((c * 4 + quad) ^ (r & 7)) * 8];
      }
#pragma unroll
      for (int i = 0; i < NM; i++)
#pragma unroll
        for (int j = 0; j < NN; j++)
          acc[i][j] = MFMA16(af[i], bfr[j], acc[i][j]);
    }
    __syncthreads();
  }

  bf16* dst = part + (size_t)blockIdx.z * (4096 * 1024);
#pragma unroll
  for (int half = 0; half < 2; half++) {
    if ((wave >> 1) == half) {
#pragma unroll
      for (int i = 0; i < NM; i++)
#pragma unroll
        for (int j = 0; j < NN; j++)
#pragma unroll
          for (int r = 0; r < 4; r++)
            Cs[(i * 16 + quad * 4 + r) * LDC + wn0 + j * 16 + l16] =
                (bf16)acc[i][j][r];
    }
    __syncthreads();
    const int c0 = (tid & 15) * 8;
#pragma unroll
    for (int it = 0; it < 4; it++) {
      int row = (tid >> 4) + it * 16;
      *(bf16x8*)&dst[(rowA0 + half * 64 + row) * 1024 + rowB0 + c0] =
          *(const bf16x8*)&Cs[row * LDC + c0];
    }
    __syncthreads();
  }
}

// ---------------------------------------------------------------------------
// out = x + sum of 4 bf16 partials
// ---------------------------------------------------------------------------
__global__ __launch_bounds__(256) void reduce_out(const float* __restrict__ x,
                                                  const bf16* __restrict__ part,
                                                  float* __restrict__ out) {
  const size_t i = ((size_t)blockIdx.x * 256 + threadIdx.x) * 8;
  constexpr size_t SL = 4096 * 1024;
  float r[8];
  float4 x0 = *(const float4*)&x[i];
  float4 x1 = *(const float4*)&x[i + 4];
  r[0] = x0.x; r[1] = x0.y; r[2] = x0.z; r[3] = x0.w;
  r[4] = x1.x; r[5] = x1.y; r[6] = x1.z; r[7] = x1.w;
#pragma unroll
  for (int z = 0; z < 4; z++) {
    bf16x8 p = *(const bf16x8*)&part[z * SL + i];
#pragma unroll
    for (int k = 0; k < 8; k++) r[k] += (float)p[k];
  }
  float4 o0 = {r[0], r[1], r[2], r[3]};
  float4 o1 = {r[4], r[5], r[6], r[7]};
  *(float4*)&out[i] = o0;
  *(float4*)&out[i + 4] = o1;
}

// ---------------------------------------------------------------------------
extern "C" void kernel_launch(void* const* d_in, const int* in_sizes, int n_in,
                              void* d_out, int out_size, void* d_ws, size_t ws_size,
                              hipStream_t stream) {
  const float* x      = (const float*)d_in[0];
  const float* ln_w   = (const float*)d_in[1];
  const float* ln_b   = (const float*)d_in[2];
  const float* w_in   = (const float*)d_in[3];  // [1024,11264]
  const float* w_attn = (const float*)d_in[4];  // [1024,1024]
  const float* w_ff   = (const float*)d_in[5];  // [4096,1024]
  float* out = (float*)d_out;
  char* ws = (char*)d_ws;

  bf16* wt_in = (bf16*)(ws);                 // [11264][1024] 23068672 B
  bf16* wtcat = (bf16*)(ws + 23068672);      // [1024][5120]  10485760 B
  bf16* xn    = (bf16*)(ws + 33554432);      // [4096][1024]   8388608 B
  bf16* proj  = (bf16*)(ws + 41943040);      // [4096][3072]  25165824 B
  bf16* part  = (bf16*)(ws + 67108864);      // 4x[4096][1024] 33554432 B
  bf16* vt    = (bf16*)(ws + 100663296);     // [32][64][2048]  8388608 B
  bf16* hcat  = (bf16*)(ws + 134217728);     // [4096][5120]  41943040 B

  prep<<<20480, 256, 0, stream>>>(w_in, w_attn, w_ff, wt_in, wtcat,
                                  x, ln_w, ln_b, xn);
  gemm_proj<<<dim3(88, 32), 256, 0, stream>>>(xn, wt_in, proj, hcat);
  vtrans<<<dim3(32, 16, 2), 256, 0, stream>>>(proj, vt);
  flash_attn<<<dim3(32, 16, 2), 256, 0, stream>>>(proj, vt, hcat);
  gemm_out<<<dim3(8, 32, 4), 256, 0, stream>>>(hcat, wtcat, part);
  reduce_out<<<2048, 256, 0, stream>>>(x, part, out);
}